// Round 1
// 282.556 us; speedup vs baseline: 1.0112x; 1.0112x over previous
//
#include <hip/hip_runtime.h>
#include <hip/hip_fp16.h>
#include <math.h>

// ---------------------------------------------------------------------------
// ADSAGE: 2x SAGEConv (mean aggr) + softmax + GCNConv, fp32.
// Aggregate-after-GEMM (mean is linear). GEMMs on matrix cores via
// split-bf16 (3-term). CSR via 2-pass radix sort by dst. ALL intermediate
// activations (p16, q16, r16, s16, tp16) stored FP16. Register-resident
// fusion: gather lands directly in MFMA A-fragment layout.
// THIS REV: the two fused gather+GEMM kernels were latency-bound
// (MfmaUtil 3%, HBM 27%, occupancy 21% -> bytes-in-flight limited by wave
// count: 782 blocks = 12 waves/CU). Now each 16-node tile is served by a
// PAIR of waves splitting the edge list (32 nodes/block -> 2x waves,
// ~24/CU); partials exchanged via XOR-swizzled LDS (16KB, <=2-way conflict
// = free), MFMA tiles split across the pair. gcn_agg gather widened to
// __half2 (2 features/lane, 2-edge parity, shfl_xor(32) combine).
// Pipeline:
//   p16,q16 = x @ [W1l|W1r]                      gemm1 (A-loads hoisted)
//   r16,s16 = relu(mean(p16)+q16+b1l) @ [W2l|W2r]  FUSED pair-split gather+GEMM
//   tp16  = softmax(mean(r16)+s16+b2l) @ Wg * dinv FUSED pair-split
//   out   = dinv*(sum_j tp[j] + tp[i]) + bg        gather (half2 lanes)
// ---------------------------------------------------------------------------

typedef __attribute__((ext_vector_type(8))) short bf16x8;
typedef __attribute__((ext_vector_type(4))) float f32x4;

__device__ inline unsigned short f32_bf16_hi(float f) {
    unsigned int u = __builtin_bit_cast(unsigned int, f);
    u = (u + 0x7FFFu + ((u >> 16) & 1u)) >> 16;
    return (unsigned short)u;
}
__device__ inline float bf16_to_f32(unsigned short h) {
    unsigned int u = ((unsigned int)h) << 16;
    return __builtin_bit_cast(float, u);
}

union H8 { float4 f4; __half2 h[4]; };

// ----------------------- radix CSR build (by dst) --------------------------
__global__ void count_kernel(const int* __restrict__ dst, int* __restrict__ off,
                             int E, int NB, int BK) {
    __shared__ int hist[256];
    int t = threadIdx.x;
    hist[t] = 0;
    __syncthreads();
    int base = blockIdx.x * 8192;
    for (int i = t; i < 8192; i += 256) {
        int e = base + i;
        if (e < E) atomicAdd(&hist[dst[e] >> 8], 1);
    }
    __syncthreads();
    if (t < BK) off[1 + t * NB + blockIdx.x] = hist[t];
    if (blockIdx.x == 0 && t == 0) off[0] = 0;
}

__global__ void scan_reduce_kernel(const int* __restrict__ data, int* __restrict__ bsum, int n) {
    __shared__ int red[256];
    int t = threadIdx.x;
    int base = blockIdx.x * 2048 + t * 8;
    int s = 0;
    if (base + 8 <= n) {
        int4 a = *(const int4*)(data + base);
        int4 b = *(const int4*)(data + base + 4);
        s = a.x + a.y + a.z + a.w + b.x + b.y + b.z + b.w;
    } else {
        for (int i = 0; i < 8; ++i)
            if (base + i < n) s += data[base + i];
    }
    red[t] = s;
    __syncthreads();
    for (int off = 128; off > 0; off >>= 1) {
        if (t < off) red[t] += red[t + off];
        __syncthreads();
    }
    if (t == 0) bsum[blockIdx.x] = red[0];
}

__global__ void scan_offsets_kernel(int* __restrict__ bsum, int B) {
    if (threadIdx.x == 0 && blockIdx.x == 0) {
        int run = 0;
        for (int i = 0; i < B; ++i) { int v = bsum[i]; bsum[i] = run; run += v; }
    }
}

__global__ void scan_final_kernel(int* __restrict__ data, const int* __restrict__ bsum, int n) {
    __shared__ int tsum[256];
    int t = threadIdx.x;
    int base = blockIdx.x * 2048 + t * 8;
    int v[8];
    int s = 0;
#pragma unroll
    for (int i = 0; i < 8; ++i) {
        v[i] = (base + i < n) ? data[base + i] : 0;
        s += v[i];
    }
    tsum[t] = s;
    for (int off = 1; off < 256; off <<= 1) {
        __syncthreads();
        int u = (t >= off) ? tsum[t - off] : 0;
        __syncthreads();
        tsum[t] += u;
    }
    __syncthreads();
    int run = bsum[blockIdx.x] + tsum[t] - s;
#pragma unroll
    for (int i = 0; i < 8; ++i) {
        run += v[i];
        if (base + i < n) data[base + i] = run;
    }
}

__global__ void partition_kernel(const int* __restrict__ src, const int* __restrict__ dst,
                                 const int* __restrict__ off, unsigned* __restrict__ ebuf,
                                 int E, int NB, int BK) {
    __shared__ int cur[256];
    int t = threadIdx.x;
    if (t < BK) cur[t] = off[t * NB + blockIdx.x];
    __syncthreads();
    int base = blockIdx.x * 8192;
    for (int i = t; i < 8192; i += 256) {
        int e = base + i;
        if (e < E) {
            int d = dst[e];
            int pos = atomicAdd(&cur[d >> 8], 1);
            ebuf[pos] = ((unsigned)src[e] << 8) | (unsigned)(d & 255);
        }
    }
}

__global__ void finalize_kernel(const unsigned* __restrict__ ebuf, const int* __restrict__ off,
                                int* __restrict__ col, int* __restrict__ rowptr,
                                float* __restrict__ dinv, int N, int NB, int E) {
    __shared__ int hist[256], scn[256], cur[256];
    int b = blockIdx.x, t = threadIdx.x;
    int base = off[b * NB];
    int end  = off[(b + 1) * NB];
    int M = end - base;
    hist[t] = 0;
    __syncthreads();
    for (int i = t; i < M; i += 256) atomicAdd(&hist[ebuf[base + i] & 255u], 1);
    __syncthreads();
    scn[t] = hist[t];
    for (int o = 1; o < 256; o <<= 1) {
        __syncthreads();
        int u = (t >= o) ? scn[t - o] : 0;
        __syncthreads();
        scn[t] += u;
    }
    __syncthreads();
    int excl = scn[t] - hist[t];
    int node = b * 256 + t;
    if (node < N) {
        rowptr[node] = base + excl;
        dinv[node] = rsqrtf((float)(hist[t] + 1));
    }
    if (b == 0 && t == 0) rowptr[N] = E;
    cur[t] = base + excl;
    __syncthreads();
    for (int i = t; i < M; i += 256) {
        unsigned w = ebuf[base + i];
        int pos = atomicAdd(&cur[w & 255u], 1);
        col[pos] = (int)(w >> 8);
    }
}

// -------------------------- weight pre-pack --------------------------------
__global__ void packw_kernel(const float* __restrict__ W1l, const float* __restrict__ W1r,
                             const float* __restrict__ W2l, const float* __restrict__ W2r,
                             const float* __restrict__ Wg,
                             unsigned short* __restrict__ p1h, unsigned short* __restrict__ p1l,
                             unsigned short* __restrict__ p2h, unsigned short* __restrict__ p2l,
                             unsigned short* __restrict__ p3h, unsigned short* __restrict__ p3l) {
    int which = blockIdx.y;
    const float* W;
    unsigned short *hi, *lo;
    int K, Mp, colOff, T;
    if (which == 0)      { W = W1l; hi = p1h; lo = p1l; K = 128; Mp = 128; colOff = 0;   T = 16; }
    else if (which == 1) { W = W1r; hi = p1h; lo = p1l; K = 128; Mp = 128; colOff = 128; T = 16; }
    else if (which == 2) { W = W2l; hi = p2h; lo = p2l; K = 128; Mp = 64;  colOff = 0;   T = 8;  }
    else if (which == 3) { W = W2r; hi = p2h; lo = p2l; K = 128; Mp = 64;  colOff = 64;  T = 8;  }
    else                 { W = Wg;  hi = p3h; lo = p3l; K = 64;  Mp = 64;  colOff = 0;   T = 4;  }
    int idx = blockIdx.x * blockDim.x + threadIdx.x;
    if (idx >= K * Mp) return;
    int k = idx / Mp, m = idx % Mp;
    float w = W[(size_t)k * Mp + m];
    int colI = colOff + m;
    int s = k >> 5, kk = k & 31, qq = kk >> 3, j = kk & 7;
    int tt = colI >> 4, n = colI & 15;
    int lane = qq * 16 + n;
    size_t pos = ((size_t)(s * T + tt) * 64 + lane) * 8 + j;
    unsigned short h = f32_bf16_hi(w);
    hi[pos] = h;
    lo[pos] = f32_bf16_hi(w - bf16_to_f32(h));
}

// --------------------------- gemm1 (K=128, M=256) --------------------------
__launch_bounds__(256)
__global__ void gemm1_kernel(const float* __restrict__ A,
                             const unsigned short* __restrict__ Whi,
                             const unsigned short* __restrict__ Wlo,
                             __half* __restrict__ outA, __half* __restrict__ outB, int N) {
    constexpr int Ttot = 16, TB = 8;
    const int lane = threadIdx.x & 63;
    const int wave = threadIdx.x >> 6;
    const int m = lane & 15, q = lane >> 4;
    const int t0 = blockIdx.y * TB;
    const int row0 = blockIdx.x * 64 + wave * 16;
    int arow = row0 + m;
    if (arow >= N) arow = N - 1;
    const float* ap = A + (size_t)arow * 128 + q * 8;

    // hoist ALL A loads
    float av[4][8];
#pragma unroll
    for (int s = 0; s < 4; ++s) {
        *(float4*)(av[s])     = *(const float4*)(ap + s * 32);
        *(float4*)(av[s] + 4) = *(const float4*)(ap + s * 32 + 4);
    }
    bf16x8 ahi[4], alo[4];
#pragma unroll
    for (int s = 0; s < 4; ++s)
#pragma unroll
        for (int i = 0; i < 8; ++i) {
            unsigned short h = f32_bf16_hi(av[s][i]);
            ahi[s][i] = (short)h;
            alo[s][i] = (short)f32_bf16_hi(av[s][i] - bf16_to_f32(h));
        }

    f32x4 acc[TB];
#pragma unroll
    for (int t = 0; t < TB; ++t) acc[t] = (f32x4)(0.f);
    const bf16x8* whp = (const bf16x8*)Whi;
    const bf16x8* wlp = (const bf16x8*)Wlo;
#pragma unroll
    for (int s = 0; s < 4; ++s) {
        const int base = (s * Ttot + t0) * 64 + lane;
#pragma unroll
        for (int t = 0; t < TB; ++t) {
            bf16x8 wh = whp[base + t * 64];
            bf16x8 wl = wlp[base + t * 64];
            acc[t] = __builtin_amdgcn_mfma_f32_16x16x32_bf16(ahi[s], wh, acc[t], 0, 0, 0);
            acc[t] = __builtin_amdgcn_mfma_f32_16x16x32_bf16(alo[s], wh, acc[t], 0, 0, 0);
            acc[t] = __builtin_amdgcn_mfma_f32_16x16x32_bf16(ahi[s], wl, acc[t], 0, 0, 0);
        }
    }

#pragma unroll
    for (int r = 0; r < 4; ++r) {
        int row = row0 + q * 4 + r;
        if (row < N) {
            __half* op = (blockIdx.y == 0) ? outA : outB;
#pragma unroll
            for (int t = 0; t < TB; ++t) {
                int c = (t0 + t) * 16 + m - blockIdx.y * 128;
                op[(size_t)row * 128 + c] = __float2half(acc[t][r]);
            }
        }
    }
}

// ------------------- FUSED: agg1+relu+gemm2 (K=128) ------------------------
// Pair-split: 32 nodes/block (2 tile-groups x 16 nodes); each group is
// served by a PAIR of waves splitting the edge list. Partials exchanged via
// XOR-swizzled LDS in two 16KB-footprint chunks; MFMA tiles split across
// the pair (wave0 -> r16 cols, wave1 -> s16 cols).
__launch_bounds__(256)
__global__ void sage2_fused_kernel(const __half* __restrict__ p16, const __half* __restrict__ q16,
                                   const int* __restrict__ rowptr, const int* __restrict__ col,
                                   const float* __restrict__ b1l,
                                   const unsigned short* __restrict__ Whi,
                                   const unsigned short* __restrict__ Wlo,
                                   __half* __restrict__ r16, __half* __restrict__ s16, int N) {
    __shared__ float part[4][64][16];
    const int lane = threadIdx.x & 63;
    const int wave = threadIdx.x >> 6;
    const int pairH = wave & 1;          // half of the edge list
    const int grp   = wave >> 1;         // 16-node group within block
    const int m = lane & 15, q = lane >> 4;
    const int row0 = blockIdx.x * 32 + grp * 16;
    int node = row0 + m;
    int nclamp = (node < N) ? node : (N - 1);
    int sAll = rowptr[nclamp];
    int eAll = (node < N) ? rowptr[nclamp + 1] : sAll;
    int deg  = eAll - sAll;
    int half0 = (deg + 1) >> 1;
    int sIdx = sAll + (pairH ? half0 : 0);
    int eIdx = pairH ? eAll : (sAll + half0);

    float acc[4][8];
#pragma unroll
    for (int s = 0; s < 4; ++s)
#pragma unroll
        for (int i = 0; i < 8; ++i) acc[s][i] = 0.f;

    const __half* pb = p16 + q * 8;
    int ptr = sIdx;
    for (; ptr + 4 <= eIdx; ptr += 4) {
        int j0 = col[ptr], j1 = col[ptr + 1], j2 = col[ptr + 2], j3 = col[ptr + 3];
        H8 u[4][4];
#pragma unroll
        for (int s = 0; s < 4; ++s) {
            u[0][s].f4 = *(const float4*)(pb + (size_t)j0 * 128 + s * 32);
            u[1][s].f4 = *(const float4*)(pb + (size_t)j1 * 128 + s * 32);
            u[2][s].f4 = *(const float4*)(pb + (size_t)j2 * 128 + s * 32);
            u[3][s].f4 = *(const float4*)(pb + (size_t)j3 * 128 + s * 32);
        }
#pragma unroll
        for (int s = 0; s < 4; ++s)
#pragma unroll
            for (int k = 0; k < 4; ++k) {
                float2 f0 = __half22float2(u[0][s].h[k]);
                float2 f1 = __half22float2(u[1][s].h[k]);
                float2 f2 = __half22float2(u[2][s].h[k]);
                float2 f3 = __half22float2(u[3][s].h[k]);
                acc[s][2 * k]     += (f0.x + f1.x) + (f2.x + f3.x);
                acc[s][2 * k + 1] += (f0.y + f1.y) + (f2.y + f3.y);
            }
    }
    for (; ptr < eIdx; ++ptr) {
        int j0 = col[ptr];
#pragma unroll
        for (int s = 0; s < 4; ++s) {
            H8 u0;
            u0.f4 = *(const float4*)(pb + (size_t)j0 * 128 + s * 32);
#pragma unroll
            for (int k = 0; k < 4; ++k) {
                float2 f0 = __half22float2(u0.h[k]);
                acc[s][2 * k]     += f0.x;
                acc[s][2 * k + 1] += f0.y;
            }
        }
    }

    // cross-wave combine: two chunks of 4 float4 slots each, XOR-swizzled
    // (bank group = (sl^ (lane&3))*4 -> <=2-way conflict, free).
    float* ap = &acc[0][0];
    const int swz = lane & 3;
#pragma unroll
    for (int c = 0; c < 2; ++c) {
        if (c) __syncthreads();
#pragma unroll
        for (int sl = 0; sl < 4; ++sl)
            *(float4*)&part[wave][lane][(sl ^ swz) * 4] =
                *(const float4*)(ap + (c * 4 + sl) * 4);
        __syncthreads();
#pragma unroll
        for (int sl = 0; sl < 4; ++sl) {
            float4 pv = *(const float4*)&part[wave ^ 1][lane][(sl ^ swz) * 4];
            int g = (c * 4 + sl) * 4;
            ap[g]     += pv.x;
            ap[g + 1] += pv.y;
            ap[g + 2] += pv.z;
            ap[g + 3] += pv.w;
        }
    }

    float inv = 1.0f / fmaxf((float)deg, 1.0f);
    bf16x8 ahi[4], alo[4];
#pragma unroll
    for (int s = 0; s < 4; ++s) {
        H8 qv;
        qv.f4 = *(const float4*)(q16 + (size_t)nclamp * 128 + s * 32 + q * 8);
        float bv[8];
        *(float4*)(bv)     = *(const float4*)(b1l + s * 32 + q * 8);
        *(float4*)(bv + 4) = *(const float4*)(b1l + s * 32 + q * 8 + 4);
#pragma unroll
        for (int i = 0; i < 8; ++i) {
            float qf = __half2float(((const __half*)&qv)[i]);
            float h = fmaxf(acc[s][i] * inv + qf + bv[i], 0.f);
            unsigned short hb = f32_bf16_hi(h);
            ahi[s][i] = (short)hb;
            alo[s][i] = (short)f32_bf16_hi(h - bf16_to_f32(hb));
        }
    }

    // MFMA: this wave computes tiles tg = pairH*4 + t (t=0..3)
    f32x4 accm[4];
#pragma unroll
    for (int t = 0; t < 4; ++t) accm[t] = (f32x4)(0.f);
    const bf16x8* whp = (const bf16x8*)Whi;
    const bf16x8* wlp = (const bf16x8*)Wlo;
#pragma unroll
    for (int s = 0; s < 4; ++s) {
        const int base = (s * 8 + pairH * 4) * 64 + lane;
#pragma unroll
        for (int t = 0; t < 4; ++t) {
            bf16x8 wh = whp[base + t * 64];
            bf16x8 wl = wlp[base + t * 64];
            accm[t] = __builtin_amdgcn_mfma_f32_16x16x32_bf16(ahi[s], wh, accm[t], 0, 0, 0);
            accm[t] = __builtin_amdgcn_mfma_f32_16x16x32_bf16(alo[s], wh, accm[t], 0, 0, 0);
            accm[t] = __builtin_amdgcn_mfma_f32_16x16x32_bf16(ahi[s], wl, accm[t], 0, 0, 0);
        }
    }
    __half* op = pairH ? s16 : r16;
#pragma unroll
    for (int r = 0; r < 4; ++r) {
        int row = row0 + q * 4 + r;
        if (row < N) {
#pragma unroll
            for (int t = 0; t < 4; ++t) {
                int c = t * 16 + m;                 // column within this half
                op[(size_t)row * 64 + c] = __float2half(accm[t][r]);
            }
        }
    }
}

// --------------- FUSED: agg2+softmax+gemm3 (K=64, dinv scale) --------------
// Same pair-split structure; 16-float partial exchange in one 16KB chunk.
__launch_bounds__(256)
__global__ void gcn_prep_fused_kernel(const __half* __restrict__ r16, const __half* __restrict__ s16,
                                      const int* __restrict__ rowptr, const int* __restrict__ col,
                                      const float* __restrict__ b2l,
                                      const unsigned short* __restrict__ Whi,
                                      const unsigned short* __restrict__ Wlo,
                                      const float* __restrict__ dinv,
                                      __half* __restrict__ tp16, int N) {
    __shared__ float part[4][64][16];
    const int lane = threadIdx.x & 63;
    const int wave = threadIdx.x >> 6;
    const int pairH = wave & 1;
    const int grp   = wave >> 1;
    const int m = lane & 15, q = lane >> 4;
    const int row0 = blockIdx.x * 32 + grp * 16;
    int node = row0 + m;
    int nclamp = (node < N) ? node : (N - 1);
    int sAll = rowptr[nclamp];
    int eAll = (node < N) ? rowptr[nclamp + 1] : sAll;
    int deg  = eAll - sAll;
    int half0 = (deg + 1) >> 1;
    int sIdx = sAll + (pairH ? half0 : 0);
    int eIdx = pairH ? eAll : (sAll + half0);

    float acc[2][8];
#pragma unroll
    for (int s = 0; s < 2; ++s)
#pragma unroll
        for (int i = 0; i < 8; ++i) acc[s][i] = 0.f;

    const __half* rb = r16 + q * 8;
    int ptr = sIdx;
    for (; ptr + 4 <= eIdx; ptr += 4) {
        int j0 = col[ptr], j1 = col[ptr + 1], j2 = col[ptr + 2], j3 = col[ptr + 3];
        H8 u[4][2];
#pragma unroll
        for (int s = 0; s < 2; ++s) {
            u[0][s].f4 = *(const float4*)(rb + (size_t)j0 * 64 + s * 32);
            u[1][s].f4 = *(const float4*)(rb + (size_t)j1 * 64 + s * 32);
            u[2][s].f4 = *(const float4*)(rb + (size_t)j2 * 64 + s * 32);
            u[3][s].f4 = *(const float4*)(rb + (size_t)j3 * 64 + s * 32);
        }
#pragma unroll
        for (int s = 0; s < 2; ++s)
#pragma unroll
            for (int k = 0; k < 4; ++k) {
                float2 f0 = __half22float2(u[0][s].h[k]);
                float2 f1 = __half22float2(u[1][s].h[k]);
                float2 f2 = __half22float2(u[2][s].h[k]);
                float2 f3 = __half22float2(u[3][s].h[k]);
                acc[s][2 * k]     += (f0.x + f1.x) + (f2.x + f3.x);
                acc[s][2 * k + 1] += (f0.y + f1.y) + (f2.y + f3.y);
            }
    }
    for (; ptr < eIdx; ++ptr) {
        int j0 = col[ptr];
#pragma unroll
        for (int s = 0; s < 2; ++s) {
            H8 u0;
            u0.f4 = *(const float4*)(rb + (size_t)j0 * 64 + s * 32);
#pragma unroll
            for (int k = 0; k < 4; ++k) {
                float2 f0 = __half22float2(u0.h[k]);
                acc[s][2 * k]     += f0.x;
                acc[s][2 * k + 1] += f0.y;
            }
        }
    }

    // cross-wave combine: single chunk (4 float4 slots), XOR-swizzled
    float* ap = &acc[0][0];
    const int swz = lane & 3;
#pragma unroll
    for (int sl = 0; sl < 4; ++sl)
        *(float4*)&part[wave][lane][(sl ^ swz) * 4] = *(const float4*)(ap + sl * 4);
    __syncthreads();
#pragma unroll
    for (int sl = 0; sl < 4; ++sl) {
        float4 pv = *(const float4*)&part[wave ^ 1][lane][(sl ^ swz) * 4];
        ap[sl * 4]     += pv.x;
        ap[sl * 4 + 1] += pv.y;
        ap[sl * 4 + 2] += pv.z;
        ap[sl * 4 + 3] += pv.w;
    }

    float inv = 1.0f / fmaxf((float)deg, 1.0f);
    float v[2][8];
    float mx = -1e30f;
#pragma unroll
    for (int s = 0; s < 2; ++s) {
        H8 sv;
        sv.f4 = *(const float4*)(s16 + (size_t)nclamp * 64 + s * 32 + q * 8);
        float bv[8];
        *(float4*)(bv)     = *(const float4*)(b2l + s * 32 + q * 8);
        *(float4*)(bv + 4) = *(const float4*)(b2l + s * 32 + q * 8 + 4);
#pragma unroll
        for (int i = 0; i < 8; ++i) {
            float sf = __half2float(((const __half*)&sv)[i]);
            v[s][i] = acc[s][i] * inv + sf + bv[i];
            mx = fmaxf(mx, v[s][i]);
        }
    }
    mx = fmaxf(mx, __shfl_xor(mx, 16, 64));
    mx = fmaxf(mx, __shfl_xor(mx, 32, 64));
    float sm = 0.f;
#pragma unroll
    for (int s = 0; s < 2; ++s)
#pragma unroll
        for (int i = 0; i < 8; ++i) {
            v[s][i] = expf(v[s][i] - mx);
            sm += v[s][i];
        }
    sm += __shfl_xor(sm, 16, 64);
    sm += __shfl_xor(sm, 32, 64);
    float is = 1.0f / sm;

    bf16x8 ahi[2], alo[2];
#pragma unroll
    for (int s = 0; s < 2; ++s)
#pragma unroll
        for (int i = 0; i < 8; ++i) {
            float h = v[s][i] * is;
            unsigned short hb = f32_bf16_hi(h);
            ahi[s][i] = (short)hb;
            alo[s][i] = (short)f32_bf16_hi(h - bf16_to_f32(hb));
        }

    // MFMA: this wave computes tiles tg = pairH*2 + t (t=0..1)
    f32x4 accm[2];
#pragma unroll
    for (int t = 0; t < 2; ++t) accm[t] = (f32x4)(0.f);
    const bf16x8* whp = (const bf16x8*)Whi;
    const bf16x8* wlp = (const bf16x8*)Wlo;
#pragma unroll
    for (int s = 0; s < 2; ++s) {
        const int base = (s * 4 + pairH * 2) * 64 + lane;
#pragma unroll
        for (int t = 0; t < 2; ++t) {
            bf16x8 wh = whp[base + t * 64];
            bf16x8 wl = wlp[base + t * 64];
            accm[t] = __builtin_amdgcn_mfma_f32_16x16x32_bf16(ahi[s], wh, accm[t], 0, 0, 0);
            accm[t] = __builtin_amdgcn_mfma_f32_16x16x32_bf16(alo[s], wh, accm[t], 0, 0, 0);
            accm[t] = __builtin_amdgcn_mfma_f32_16x16x32_bf16(ahi[s], wl, accm[t], 0, 0, 0);
        }
    }
#pragma unroll
    for (int r = 0; r < 4; ++r) {
        int row = row0 + q * 4 + r;
        if (row < N) {
            float sc = dinv[row];
#pragma unroll
            for (int t = 0; t < 2; ++t) {
                int c = (pairH * 2 + t) * 16 + m;
                tp16[(size_t)row * 64 + c] = __float2half(accm[t][r] * sc);
            }
        }
    }
}

// ------------------------------ gcn gather ---------------------------------
// half2 lanes: 32 feature-pair lanes x 2 edge-parity groups; combine via
// shfl_xor(32). Doubles bytes-in-flight per load instruction vs scalar half.
__global__ void gcn_agg_kernel(const __half* __restrict__ tp,
                               const int* __restrict__ rowptr, const int* __restrict__ col,
                               const float* __restrict__ dinv, const float* __restrict__ bg,
                               float* __restrict__ out, int N) {
    int node = blockIdx.x * 4 + (threadIdx.x >> 6);
    if (node >= N) return;
    int lane = threadIdx.x & 63;
    int f2 = lane & 31;   // features 2*f2, 2*f2+1
    int ep = lane >> 5;   // edge parity
    int s = rowptr[node], e = rowptr[node + 1];
    float ax[8], ay[8];
#pragma unroll
    for (int k = 0; k < 8; ++k) { ax[k] = 0.f; ay[k] = 0.f; }
    int p = s;
    for (; p + 16 <= e; p += 16) {
#pragma unroll
        for (int k = 0; k < 8; ++k) {
            int j = col[p + 2 * k + ep];
            float2 f = __half22float2(*(const __half2*)(tp + (size_t)j * 64 + 2 * f2));
            ax[k] += f.x;
            ay[k] += f.y;
        }
    }
    for (int t = p + ep; t < e; t += 2) {
        int j = col[t];
        float2 f = __half22float2(*(const __half2*)(tp + (size_t)j * 64 + 2 * f2));
        ax[0] += f.x;
        ay[0] += f.y;
    }
    float sx = ((ax[0] + ax[1]) + (ax[2] + ax[3])) + ((ax[4] + ax[5]) + (ax[6] + ax[7]));
    float sy = ((ay[0] + ay[1]) + (ay[2] + ay[3])) + ((ay[4] + ay[5]) + (ay[6] + ay[7]));
    sx += __shfl_xor(sx, 32, 64);
    sy += __shfl_xor(sy, 32, 64);
    if (ep == 0) {
        float2 selfv = __half22float2(*(const __half2*)(tp + (size_t)node * 64 + 2 * f2));
        float di = dinv[node];
        float2 o;
        o.x = (sx + selfv.x) * di + bg[2 * f2];
        o.y = (sy + selfv.y) * di + bg[2 * f2 + 1];
        *(float2*)(out + (size_t)node * 64 + 2 * f2) = o;
    }
}

extern "C" void kernel_launch(void* const* d_in, const int* in_sizes, int n_in,
                              void* d_out, int out_size, void* d_ws, size_t ws_size,
                              hipStream_t stream) {
    const float* x = (const float*)d_in[0];
    const int* ei = (const int*)d_in[1];    // int32 per harness conversion
    const float* W1l = (const float*)d_in[2];
    const float* b1l = (const float*)d_in[3];
    const float* W1r = (const float*)d_in[4];
    const float* W2l = (const float*)d_in[5];
    const float* b2l = (const float*)d_in[6];
    const float* W2r = (const float*)d_in[7];
    const float* Wg  = (const float*)d_in[8];
    const float* bg  = (const float*)d_in[9];

    const int N = in_sizes[0] / 128;
    const int E = in_sizes[1] / 2;
    const int* srcp = ei;
    const int* dstp = ei + E;

    const int NB = (E + 8191) / 8192;
    const int BK = (N + 255) >> 8;
    const int len = BK * NB;

    // workspace layout
    float* ws = (float*)d_ws;
    float* dinv = ws;                          // N
    __half* p16 = (__half*)(dinv + N);         // N*128 half
    __half* q16 = p16 + (size_t)N * 128;       // N*128 half
    __half* r16 = q16 + (size_t)N * 128;       // N*64 half
    __half* s16 = r16 + (size_t)N * 64;        // N*64 half
    __half* tp16 = s16 + (size_t)N * 64;       // N*64 half
    int* rowptr = (int*)(tp16 + (size_t)N * 64); // N+1
    int* off    = rowptr + (N + 1);            // len+2
    int* colbuf = off + len + 2;               // E
    unsigned* ebuf = (unsigned*)(colbuf + E);  // E
    int* bsum   = (int*)(ebuf + E);            // 32
    uintptr_t up = (uintptr_t)(bsum + 32);
    up = (up + 15) & ~(uintptr_t)15;
    unsigned short* p1h = (unsigned short*)up; // 32768 (128x256)
    unsigned short* p1l = p1h + 32768;
    unsigned short* p2h = p1l + 32768;         // 16384 (128x128)
    unsigned short* p2l = p2h + 16384;
    unsigned short* p3h = p2l + 16384;         // 4096 (64x64)
    unsigned short* p3l = p3h + 4096;

    float* out = (float*)d_out;

    // --- CSR build (radix by dst) ---
    count_kernel<<<NB, 256, 0, stream>>>(dstp, off, E, NB, BK);
    const int sn = len + 1;
    const int SBs = (sn + 2047) / 2048;
    scan_reduce_kernel<<<SBs, 256, 0, stream>>>(off, bsum, sn);
    scan_offsets_kernel<<<1, 64, 0, stream>>>(bsum, SBs);
    scan_final_kernel<<<SBs, 256, 0, stream>>>(off, bsum, sn);
    partition_kernel<<<NB, 256, 0, stream>>>(srcp, dstp, off, ebuf, E, NB, BK);
    finalize_kernel<<<BK, 256, 0, stream>>>(ebuf, off, colbuf, rowptr, dinv, N, NB, E);

    packw_kernel<<<dim3(64, 5), 256, 0, stream>>>(W1l, W1r, W2l, W2r, Wg,
                                                  p1h, p1l, p2h, p2l, p3h, p3l);

    const int gb  = (N + 63) / 64;   // gemm1: 64 nodes/block
    const int gbf = (N + 31) / 32;   // fused kernels: 32 nodes/block (pair-split)
    const int ab  = (N + 3) / 4;

    // gemm1: A-loads hoisted; y=0 -> p16, y=1 -> q16
    gemm1_kernel<<<dim3(gb, 2), 256, 0, stream>>>(x, p1h, p1l, p16, q16, N);

    // fused: h1 = relu(mean(p16)+q16+b1l); [r16|s16] = h1 @ [W2l|W2r]
    sage2_fused_kernel<<<gbf, 256, 0, stream>>>(p16, q16, rowptr, colbuf, b1l,
                                                p2h, p2l, r16, s16, N);

    // fused: h2 = softmax(mean(r16)+s16+b2l); tp16 = (h2 @ Wg) * dinv
    gcn_prep_fused_kernel<<<gbf, 256, 0, stream>>>(r16, s16, rowptr, colbuf, b2l,
                                                   p3h, p3l, dinv, tp16, N);

    gcn_agg_kernel<<<ab, 256, 0, stream>>>(tp16, rowptr, colbuf, dinv, bg, out, N);
}

// Round 2
// 269.719 us; speedup vs baseline: 1.0593x; 1.0476x over previous
//
#include <hip/hip_runtime.h>
#include <hip/hip_fp16.h>
#include <math.h>

// ---------------------------------------------------------------------------
// ADSAGE: 2x SAGEConv (mean aggr) + softmax + GCNConv, fp32.
// Aggregate-after-GEMM (mean is linear). GEMMs on matrix cores via
// split-bf16 (3-term). CSR via 2-pass radix sort by dst.
// THIS REV: sage2's random gather is throughput-bound on the L2-miss path
// (~2.2 TB/s random line fills; 2x waves gave only +5%, and FETCH 117MB is
// already near the 8-XCD replication floor ~102MB). Only lever: bytes/edge.
// p16 is now stored FP8 e4m3 (OCP, native gfx950): gathered row 256B->128B
// = ONE cache line per edge instead of two -> fill traffic ~halved.
// Decode via v_cvt_pk_f32_fp8 (VALU-neutral); encode in gemm1 epilogue via
// swizzled LDS byte transpose. q16/r16/s16/tp16 stay FP16 (their rows are
// already 1 line; fp8 would buy nothing at line granularity).
// Pipeline:
//   p8,q16 = x @ [W1l|W1r]                       gemm1 (p8 = fp8 e4m3)
//   r16,s16 = relu(mean(p8)+q16+b1l) @ [W2l|W2r]   FUSED pair-split gather+GEMM
//   tp16  = softmax(mean(r16)+s16+b2l) @ Wg * dinv FUSED pair-split
//   out   = dinv*(sum_j tp[j] + tp[i]) + bg        gather (half2 lanes)
// ---------------------------------------------------------------------------

typedef __attribute__((ext_vector_type(8))) short bf16x8;
typedef __attribute__((ext_vector_type(4))) float f32x4;
typedef __attribute__((ext_vector_type(2))) float f32v2;

__device__ inline unsigned short f32_bf16_hi(float f) {
    unsigned int u = __builtin_bit_cast(unsigned int, f);
    u = (u + 0x7FFFu + ((u >> 16) & 1u)) >> 16;
    return (unsigned short)u;
}
__device__ inline float bf16_to_f32(unsigned short h) {
    unsigned int u = ((unsigned int)h) << 16;
    return __builtin_bit_cast(float, u);
}

union H8 { float4 f4; __half2 h[4]; };

// ----------------------- radix CSR build (by dst) --------------------------
__global__ void count_kernel(const int* __restrict__ dst, int* __restrict__ off,
                             int E, int NB, int BK) {
    __shared__ int hist[256];
    int t = threadIdx.x;
    hist[t] = 0;
    __syncthreads();
    int base = blockIdx.x * 8192;
    for (int i = t; i < 8192; i += 256) {
        int e = base + i;
        if (e < E) atomicAdd(&hist[dst[e] >> 8], 1);
    }
    __syncthreads();
    if (t < BK) off[1 + t * NB + blockIdx.x] = hist[t];
    if (blockIdx.x == 0 && t == 0) off[0] = 0;
}

__global__ void scan_reduce_kernel(const int* __restrict__ data, int* __restrict__ bsum, int n) {
    __shared__ int red[256];
    int t = threadIdx.x;
    int base = blockIdx.x * 2048 + t * 8;
    int s = 0;
    if (base + 8 <= n) {
        int4 a = *(const int4*)(data + base);
        int4 b = *(const int4*)(data + base + 4);
        s = a.x + a.y + a.z + a.w + b.x + b.y + b.z + b.w;
    } else {
        for (int i = 0; i < 8; ++i)
            if (base + i < n) s += data[base + i];
    }
    red[t] = s;
    __syncthreads();
    for (int off = 128; off > 0; off >>= 1) {
        if (t < off) red[t] += red[t + off];
        __syncthreads();
    }
    if (t == 0) bsum[blockIdx.x] = red[0];
}

__global__ void scan_offsets_kernel(int* __restrict__ bsum, int B) {
    if (threadIdx.x == 0 && blockIdx.x == 0) {
        int run = 0;
        for (int i = 0; i < B; ++i) { int v = bsum[i]; bsum[i] = run; run += v; }
    }
}

__global__ void scan_final_kernel(int* __restrict__ data, const int* __restrict__ bsum, int n) {
    __shared__ int tsum[256];
    int t = threadIdx.x;
    int base = blockIdx.x * 2048 + t * 8;
    int v[8];
    int s = 0;
#pragma unroll
    for (int i = 0; i < 8; ++i) {
        v[i] = (base + i < n) ? data[base + i] : 0;
        s += v[i];
    }
    tsum[t] = s;
    for (int off = 1; off < 256; off <<= 1) {
        __syncthreads();
        int u = (t >= off) ? tsum[t - off] : 0;
        __syncthreads();
        tsum[t] += u;
    }
    __syncthreads();
    int run = bsum[blockIdx.x] + tsum[t] - s;
#pragma unroll
    for (int i = 0; i < 8; ++i) {
        run += v[i];
        if (base + i < n) data[base + i] = run;
    }
}

__global__ void partition_kernel(const int* __restrict__ src, const int* __restrict__ dst,
                                 const int* __restrict__ off, unsigned* __restrict__ ebuf,
                                 int E, int NB, int BK) {
    __shared__ int cur[256];
    int t = threadIdx.x;
    if (t < BK) cur[t] = off[t * NB + blockIdx.x];
    __syncthreads();
    int base = blockIdx.x * 8192;
    for (int i = t; i < 8192; i += 256) {
        int e = base + i;
        if (e < E) {
            int d = dst[e];
            int pos = atomicAdd(&cur[d >> 8], 1);
            ebuf[pos] = ((unsigned)src[e] << 8) | (unsigned)(d & 255);
        }
    }
}

__global__ void finalize_kernel(const unsigned* __restrict__ ebuf, const int* __restrict__ off,
                                int* __restrict__ col, int* __restrict__ rowptr,
                                float* __restrict__ dinv, int N, int NB, int E) {
    __shared__ int hist[256], scn[256], cur[256];
    int b = blockIdx.x, t = threadIdx.x;
    int base = off[b * NB];
    int end  = off[(b + 1) * NB];
    int M = end - base;
    hist[t] = 0;
    __syncthreads();
    for (int i = t; i < M; i += 256) atomicAdd(&hist[ebuf[base + i] & 255u], 1);
    __syncthreads();
    scn[t] = hist[t];
    for (int o = 1; o < 256; o <<= 1) {
        __syncthreads();
        int u = (t >= o) ? scn[t - o] : 0;
        __syncthreads();
        scn[t] += u;
    }
    __syncthreads();
    int excl = scn[t] - hist[t];
    int node = b * 256 + t;
    if (node < N) {
        rowptr[node] = base + excl;
        dinv[node] = rsqrtf((float)(hist[t] + 1));
    }
    if (b == 0 && t == 0) rowptr[N] = E;
    cur[t] = base + excl;
    __syncthreads();
    for (int i = t; i < M; i += 256) {
        unsigned w = ebuf[base + i];
        int pos = atomicAdd(&cur[w & 255u], 1);
        col[pos] = (int)(w >> 8);
    }
}

// -------------------------- weight pre-pack --------------------------------
__global__ void packw_kernel(const float* __restrict__ W1l, const float* __restrict__ W1r,
                             const float* __restrict__ W2l, const float* __restrict__ W2r,
                             const float* __restrict__ Wg,
                             unsigned short* __restrict__ p1h, unsigned short* __restrict__ p1l,
                             unsigned short* __restrict__ p2h, unsigned short* __restrict__ p2l,
                             unsigned short* __restrict__ p3h, unsigned short* __restrict__ p3l) {
    int which = blockIdx.y;
    const float* W;
    unsigned short *hi, *lo;
    int K, Mp, colOff, T;
    if (which == 0)      { W = W1l; hi = p1h; lo = p1l; K = 128; Mp = 128; colOff = 0;   T = 16; }
    else if (which == 1) { W = W1r; hi = p1h; lo = p1l; K = 128; Mp = 128; colOff = 128; T = 16; }
    else if (which == 2) { W = W2l; hi = p2h; lo = p2l; K = 128; Mp = 64;  colOff = 0;   T = 8;  }
    else if (which == 3) { W = W2r; hi = p2h; lo = p2l; K = 128; Mp = 64;  colOff = 64;  T = 8;  }
    else                 { W = Wg;  hi = p3h; lo = p3l; K = 64;  Mp = 64;  colOff = 0;   T = 4;  }
    int idx = blockIdx.x * blockDim.x + threadIdx.x;
    if (idx >= K * Mp) return;
    int k = idx / Mp, m = idx % Mp;
    float w = W[(size_t)k * Mp + m];
    int colI = colOff + m;
    int s = k >> 5, kk = k & 31, qq = kk >> 3, j = kk & 7;
    int tt = colI >> 4, n = colI & 15;
    int lane = qq * 16 + n;
    size_t pos = ((size_t)(s * T + tt) * 64 + lane) * 8 + j;
    unsigned short h = f32_bf16_hi(w);
    hi[pos] = h;
    lo[pos] = f32_bf16_hi(w - bf16_to_f32(h));
}

// --------------------------- gemm1 (K=128, M=256) --------------------------
// A-loads hoisted. y=0 -> p8 (fp8 e4m3, packed via swizzled LDS byte
// transpose), y=1 -> q16 (fp16).
__launch_bounds__(256)
__global__ void gemm1_kernel(const float* __restrict__ A,
                             const unsigned short* __restrict__ Whi,
                             const unsigned short* __restrict__ Wlo,
                             unsigned char* __restrict__ outA8, __half* __restrict__ outB, int N) {
    constexpr int Ttot = 16, TB = 8;
    __shared__ __align__(16) unsigned char pk[4][16][128];
    const int lane = threadIdx.x & 63;
    const int wave = threadIdx.x >> 6;
    const int m = lane & 15, q = lane >> 4;
    const int t0 = blockIdx.y * TB;
    const int row0 = blockIdx.x * 64 + wave * 16;
    int arow = row0 + m;
    if (arow >= N) arow = N - 1;
    const float* ap = A + (size_t)arow * 128 + q * 8;

    // hoist ALL A loads
    float av[4][8];
#pragma unroll
    for (int s = 0; s < 4; ++s) {
        *(float4*)(av[s])     = *(const float4*)(ap + s * 32);
        *(float4*)(av[s] + 4) = *(const float4*)(ap + s * 32 + 4);
    }
    bf16x8 ahi[4], alo[4];
#pragma unroll
    for (int s = 0; s < 4; ++s)
#pragma unroll
        for (int i = 0; i < 8; ++i) {
            unsigned short h = f32_bf16_hi(av[s][i]);
            ahi[s][i] = (short)h;
            alo[s][i] = (short)f32_bf16_hi(av[s][i] - bf16_to_f32(h));
        }

    f32x4 acc[TB];
#pragma unroll
    for (int t = 0; t < TB; ++t) acc[t] = (f32x4)(0.f);
    const bf16x8* whp = (const bf16x8*)Whi;
    const bf16x8* wlp = (const bf16x8*)Wlo;
#pragma unroll
    for (int s = 0; s < 4; ++s) {
        const int base = (s * Ttot + t0) * 64 + lane;
#pragma unroll
        for (int t = 0; t < TB; ++t) {
            bf16x8 wh = whp[base + t * 64];
            bf16x8 wl = wlp[base + t * 64];
            acc[t] = __builtin_amdgcn_mfma_f32_16x16x32_bf16(ahi[s], wh, acc[t], 0, 0, 0);
            acc[t] = __builtin_amdgcn_mfma_f32_16x16x32_bf16(alo[s], wh, acc[t], 0, 0, 0);
            acc[t] = __builtin_amdgcn_mfma_f32_16x16x32_bf16(ahi[s], wl, acc[t], 0, 0, 0);
        }
    }

    if (blockIdx.y == 0) {
        // fp8 path: encode pairs, scatter bytes to swizzled LDS, store lines
#pragma unroll
        for (int r = 0; r < 4; ++r) {
            int row = q * 4 + r;
            int sw = (row & 3) << 5;
#pragma unroll
            for (int t = 0; t < 8; t += 2) {
                int w = __builtin_amdgcn_cvt_pk_fp8_f32(acc[t][r], acc[t + 1][r], 0, false);
                pk[wave][row][(t * 16 + m) ^ sw] = (unsigned char)(w & 0xff);
                pk[wave][row][((t + 1) * 16 + m) ^ sw] = (unsigned char)((w >> 8) & 0xff);
            }
        }
        __syncthreads();
        int rr = lane >> 2, qt = lane & 3;
        int grow = row0 + rr;
        if (grow < N) {
            const unsigned char* srcp = &pk[wave][rr][(qt ^ (rr & 3)) * 32];
            uint4 v0 = *(const uint4*)(srcp);
            uint4 v1 = *(const uint4*)(srcp + 16);
            *(uint4*)(outA8 + (size_t)grow * 128 + qt * 32) = v0;
            *(uint4*)(outA8 + (size_t)grow * 128 + qt * 32 + 16) = v1;
        }
    } else {
#pragma unroll
        for (int r = 0; r < 4; ++r) {
            int row = row0 + q * 4 + r;
            if (row < N) {
#pragma unroll
                for (int t = 0; t < TB; ++t) {
                    int c = (t0 + t) * 16 + m - 128;
                    outB[(size_t)row * 128 + c] = __float2half(acc[t][r]);
                }
            }
        }
    }
}

// ------------------- FUSED: agg1+relu+gemm2 (K=128) ------------------------
// Pair-split: 32 nodes/block; pair of waves splits each 16-node group's edge
// list; partials exchanged via XOR-swizzled LDS; MFMA tiles split across the
// pair. Gather now reads FP8 rows (128B = 1 line/edge), decode via
// v_cvt_pk_f32_fp8.
__launch_bounds__(256)
__global__ void sage2_fused_kernel(const unsigned char* __restrict__ p8, const __half* __restrict__ q16,
                                   const int* __restrict__ rowptr, const int* __restrict__ col,
                                   const float* __restrict__ b1l,
                                   const unsigned short* __restrict__ Whi,
                                   const unsigned short* __restrict__ Wlo,
                                   __half* __restrict__ r16, __half* __restrict__ s16, int N) {
    __shared__ float part[4][64][16];
    const int lane = threadIdx.x & 63;
    const int wave = threadIdx.x >> 6;
    const int pairH = wave & 1;          // half of the edge list
    const int grp   = wave >> 1;         // 16-node group within block
    const int m = lane & 15, q = lane >> 4;
    const int row0 = blockIdx.x * 32 + grp * 16;
    int node = row0 + m;
    int nclamp = (node < N) ? node : (N - 1);
    int sAll = rowptr[nclamp];
    int eAll = (node < N) ? rowptr[nclamp + 1] : sAll;
    int deg  = eAll - sAll;
    int half0 = (deg + 1) >> 1;
    int sIdx = sAll + (pairH ? half0 : 0);
    int eIdx = pairH ? eAll : (sAll + half0);

    float acc[4][8];
#pragma unroll
    for (int s = 0; s < 4; ++s)
#pragma unroll
        for (int i = 0; i < 8; ++i) acc[s][i] = 0.f;

    const unsigned char* pb = p8 + q * 8;
    int ptr = sIdx;
    for (; ptr + 4 <= eIdx; ptr += 4) {
        int j0 = col[ptr], j1 = col[ptr + 1], j2 = col[ptr + 2], j3 = col[ptr + 3];
        uint2 u[4][4];
#pragma unroll
        for (int s = 0; s < 4; ++s) {
            u[0][s] = *(const uint2*)(pb + (size_t)j0 * 128 + s * 32);
            u[1][s] = *(const uint2*)(pb + (size_t)j1 * 128 + s * 32);
            u[2][s] = *(const uint2*)(pb + (size_t)j2 * 128 + s * 32);
            u[3][s] = *(const uint2*)(pb + (size_t)j3 * 128 + s * 32);
        }
#pragma unroll
        for (int s = 0; s < 4; ++s)
#pragma unroll
            for (int e = 0; e < 4; ++e) {
                f32v2 a = __builtin_amdgcn_cvt_pk_f32_fp8(u[e][s].x, false);
                f32v2 b = __builtin_amdgcn_cvt_pk_f32_fp8(u[e][s].x, true);
                f32v2 c = __builtin_amdgcn_cvt_pk_f32_fp8(u[e][s].y, false);
                f32v2 d = __builtin_amdgcn_cvt_pk_f32_fp8(u[e][s].y, true);
                acc[s][0] += a[0]; acc[s][1] += a[1];
                acc[s][2] += b[0]; acc[s][3] += b[1];
                acc[s][4] += c[0]; acc[s][5] += c[1];
                acc[s][6] += d[0]; acc[s][7] += d[1];
            }
    }
    for (; ptr < eIdx; ++ptr) {
        int j0 = col[ptr];
#pragma unroll
        for (int s = 0; s < 4; ++s) {
            uint2 u0 = *(const uint2*)(pb + (size_t)j0 * 128 + s * 32);
            f32v2 a = __builtin_amdgcn_cvt_pk_f32_fp8(u0.x, false);
            f32v2 b = __builtin_amdgcn_cvt_pk_f32_fp8(u0.x, true);
            f32v2 c = __builtin_amdgcn_cvt_pk_f32_fp8(u0.y, false);
            f32v2 d = __builtin_amdgcn_cvt_pk_f32_fp8(u0.y, true);
            acc[s][0] += a[0]; acc[s][1] += a[1];
            acc[s][2] += b[0]; acc[s][3] += b[1];
            acc[s][4] += c[0]; acc[s][5] += c[1];
            acc[s][6] += d[0]; acc[s][7] += d[1];
        }
    }

    // cross-wave combine: two chunks of 4 float4 slots each, XOR-swizzled
    // (bank group = (sl ^ (lane&3))*4 -> <=2-way conflict, free).
    float* ap = &acc[0][0];
    const int swz = lane & 3;
#pragma unroll
    for (int c = 0; c < 2; ++c) {
        if (c) __syncthreads();
#pragma unroll
        for (int sl = 0; sl < 4; ++sl)
            *(float4*)&part[wave][lane][(sl ^ swz) * 4] =
                *(const float4*)(ap + (c * 4 + sl) * 4);
        __syncthreads();
#pragma unroll
        for (int sl = 0; sl < 4; ++sl) {
            float4 pv = *(const float4*)&part[wave ^ 1][lane][(sl ^ swz) * 4];
            int g = (c * 4 + sl) * 4;
            ap[g]     += pv.x;
            ap[g + 1] += pv.y;
            ap[g + 2] += pv.z;
            ap[g + 3] += pv.w;
        }
    }

    float inv = 1.0f / fmaxf((float)deg, 1.0f);
    bf16x8 ahi[4], alo[4];
#pragma unroll
    for (int s = 0; s < 4; ++s) {
        H8 qv;
        qv.f4 = *(const float4*)(q16 + (size_t)nclamp * 128 + s * 32 + q * 8);
        float bv[8];
        *(float4*)(bv)     = *(const float4*)(b1l + s * 32 + q * 8);
        *(float4*)(bv + 4) = *(const float4*)(b1l + s * 32 + q * 8 + 4);
#pragma unroll
        for (int i = 0; i < 8; ++i) {
            float qf = __half2float(((const __half*)&qv)[i]);
            float h = fmaxf(acc[s][i] * inv + qf + bv[i], 0.f);
            unsigned short hb = f32_bf16_hi(h);
            ahi[s][i] = (short)hb;
            alo[s][i] = (short)f32_bf16_hi(h - bf16_to_f32(hb));
        }
    }

    // MFMA: this wave computes tiles tg = pairH*4 + t (t=0..3)
    f32x4 accm[4];
#pragma unroll
    for (int t = 0; t < 4; ++t) accm[t] = (f32x4)(0.f);
    const bf16x8* whp = (const bf16x8*)Whi;
    const bf16x8* wlp = (const bf16x8*)Wlo;
#pragma unroll
    for (int s = 0; s < 4; ++s) {
        const int base = (s * 8 + pairH * 4) * 64 + lane;
#pragma unroll
        for (int t = 0; t < 4; ++t) {
            bf16x8 wh = whp[base + t * 64];
            bf16x8 wl = wlp[base + t * 64];
            accm[t] = __builtin_amdgcn_mfma_f32_16x16x32_bf16(ahi[s], wh, accm[t], 0, 0, 0);
            accm[t] = __builtin_amdgcn_mfma_f32_16x16x32_bf16(alo[s], wh, accm[t], 0, 0, 0);
            accm[t] = __builtin_amdgcn_mfma_f32_16x16x32_bf16(ahi[s], wl, accm[t], 0, 0, 0);
        }
    }
    __half* op = pairH ? s16 : r16;
#pragma unroll
    for (int r = 0; r < 4; ++r) {
        int row = row0 + q * 4 + r;
        if (row < N) {
#pragma unroll
            for (int t = 0; t < 4; ++t) {
                int c = t * 16 + m;                 // column within this half
                op[(size_t)row * 64 + c] = __float2half(accm[t][r]);
            }
        }
    }
}

// --------------- FUSED: agg2+softmax+gemm3 (K=64, dinv scale) --------------
// Same pair-split structure; 16-float partial exchange in one 16KB chunk.
__launch_bounds__(256)
__global__ void gcn_prep_fused_kernel(const __half* __restrict__ r16, const __half* __restrict__ s16,
                                      const int* __restrict__ rowptr, const int* __restrict__ col,
                                      const float* __restrict__ b2l,
                                      const unsigned short* __restrict__ Whi,
                                      const unsigned short* __restrict__ Wlo,
                                      const float* __restrict__ dinv,
                                      __half* __restrict__ tp16, int N) {
    __shared__ float part[4][64][16];
    const int lane = threadIdx.x & 63;
    const int wave = threadIdx.x >> 6;
    const int pairH = wave & 1;
    const int grp   = wave >> 1;
    const int m = lane & 15, q = lane >> 4;
    const int row0 = blockIdx.x * 32 + grp * 16;
    int node = row0 + m;
    int nclamp = (node < N) ? node : (N - 1);
    int sAll = rowptr[nclamp];
    int eAll = (node < N) ? rowptr[nclamp + 1] : sAll;
    int deg  = eAll - sAll;
    int half0 = (deg + 1) >> 1;
    int sIdx = sAll + (pairH ? half0 : 0);
    int eIdx = pairH ? eAll : (sAll + half0);

    float acc[2][8];
#pragma unroll
    for (int s = 0; s < 2; ++s)
#pragma unroll
        for (int i = 0; i < 8; ++i) acc[s][i] = 0.f;

    const __half* rb = r16 + q * 8;
    int ptr = sIdx;
    for (; ptr + 4 <= eIdx; ptr += 4) {
        int j0 = col[ptr], j1 = col[ptr + 1], j2 = col[ptr + 2], j3 = col[ptr + 3];
        H8 u[4][2];
#pragma unroll
        for (int s = 0; s < 2; ++s) {
            u[0][s].f4 = *(const float4*)(rb + (size_t)j0 * 64 + s * 32);
            u[1][s].f4 = *(const float4*)(rb + (size_t)j1 * 64 + s * 32);
            u[2][s].f4 = *(const float4*)(rb + (size_t)j2 * 64 + s * 32);
            u[3][s].f4 = *(const float4*)(rb + (size_t)j3 * 64 + s * 32);
        }
#pragma unroll
        for (int s = 0; s < 2; ++s)
#pragma unroll
            for (int k = 0; k < 4; ++k) {
                float2 f0 = __half22float2(u[0][s].h[k]);
                float2 f1 = __half22float2(u[1][s].h[k]);
                float2 f2 = __half22float2(u[2][s].h[k]);
                float2 f3 = __half22float2(u[3][s].h[k]);
                acc[s][2 * k]     += (f0.x + f1.x) + (f2.x + f3.x);
                acc[s][2 * k + 1] += (f0.y + f1.y) + (f2.y + f3.y);
            }
    }
    for (; ptr < eIdx; ++ptr) {
        int j0 = col[ptr];
#pragma unroll
        for (int s = 0; s < 2; ++s) {
            H8 u0;
            u0.f4 = *(const float4*)(rb + (size_t)j0 * 64 + s * 32);
#pragma unroll
            for (int k = 0; k < 4; ++k) {
                float2 f0 = __half22float2(u0.h[k]);
                acc[s][2 * k]     += f0.x;
                acc[s][2 * k + 1] += f0.y;
            }
        }
    }

    // cross-wave combine: single chunk (4 float4 slots), XOR-swizzled
    float* ap = &acc[0][0];
    const int swz = lane & 3;
#pragma unroll
    for (int sl = 0; sl < 4; ++sl)
        *(float4*)&part[wave][lane][(sl ^ swz) * 4] = *(const float4*)(ap + sl * 4);
    __syncthreads();
#pragma unroll
    for (int sl = 0; sl < 4; ++sl) {
        float4 pv = *(const float4*)&part[wave ^ 1][lane][(sl ^ swz) * 4];
        ap[sl * 4]     += pv.x;
        ap[sl * 4 + 1] += pv.y;
        ap[sl * 4 + 2] += pv.z;
        ap[sl * 4 + 3] += pv.w;
    }

    float inv = 1.0f / fmaxf((float)deg, 1.0f);
    float v[2][8];
    float mx = -1e30f;
#pragma unroll
    for (int s = 0; s < 2; ++s) {
        H8 sv;
        sv.f4 = *(const float4*)(s16 + (size_t)nclamp * 64 + s * 32 + q * 8);
        float bv[8];
        *(float4*)(bv)     = *(const float4*)(b2l + s * 32 + q * 8);
        *(float4*)(bv + 4) = *(const float4*)(b2l + s * 32 + q * 8 + 4);
#pragma unroll
        for (int i = 0; i < 8; ++i) {
            float sf = __half2float(((const __half*)&sv)[i]);
            v[s][i] = acc[s][i] * inv + sf + bv[i];
            mx = fmaxf(mx, v[s][i]);
        }
    }
    mx = fmaxf(mx, __shfl_xor(mx, 16, 64));
    mx = fmaxf(mx, __shfl_xor(mx, 32, 64));
    float sm = 0.f;
#pragma unroll
    for (int s = 0; s < 2; ++s)
#pragma unroll
        for (int i = 0; i < 8; ++i) {
            v[s][i] = expf(v[s][i] - mx);
            sm += v[s][i];
        }
    sm += __shfl_xor(sm, 16, 64);
    sm += __shfl_xor(sm, 32, 64);
    float is = 1.0f / sm;

    bf16x8 ahi[2], alo[2];
#pragma unroll
    for (int s = 0; s < 2; ++s)
#pragma unroll
        for (int i = 0; i < 8; ++i) {
            float h = v[s][i] * is;
            unsigned short hb = f32_bf16_hi(h);
            ahi[s][i] = (short)hb;
            alo[s][i] = (short)f32_bf16_hi(h - bf16_to_f32(hb));
        }

    // MFMA: this wave computes tiles tg = pairH*2 + t (t=0..1)
    f32x4 accm[2];
#pragma unroll
    for (int t = 0; t < 2; ++t) accm[t] = (f32x4)(0.f);
    const bf16x8* whp = (const bf16x8*)Whi;
    const bf16x8* wlp = (const bf16x8*)Wlo;
#pragma unroll
    for (int s = 0; s < 2; ++s) {
        const int base = (s * 4 + pairH * 2) * 64 + lane;
#pragma unroll
        for (int t = 0; t < 2; ++t) {
            bf16x8 wh = whp[base + t * 64];
            bf16x8 wl = wlp[base + t * 64];
            accm[t] = __builtin_amdgcn_mfma_f32_16x16x32_bf16(ahi[s], wh, accm[t], 0, 0, 0);
            accm[t] = __builtin_amdgcn_mfma_f32_16x16x32_bf16(alo[s], wh, accm[t], 0, 0, 0);
            accm[t] = __builtin_amdgcn_mfma_f32_16x16x32_bf16(ahi[s], wl, accm[t], 0, 0, 0);
        }
    }
#pragma unroll
    for (int r = 0; r < 4; ++r) {
        int row = row0 + q * 4 + r;
        if (row < N) {
            float sc = dinv[row];
#pragma unroll
            for (int t = 0; t < 2; ++t) {
                int c = (pairH * 2 + t) * 16 + m;
                tp16[(size_t)row * 64 + c] = __float2half(accm[t][r] * sc);
            }
        }
    }
}

// ------------------------------ gcn gather ---------------------------------
// half2 lanes: 32 feature-pair lanes x 2 edge-parity groups; combine via
// shfl_xor(32).
__global__ void gcn_agg_kernel(const __half* __restrict__ tp,
                               const int* __restrict__ rowptr, const int* __restrict__ col,
                               const float* __restrict__ dinv, const float* __restrict__ bg,
                               float* __restrict__ out, int N) {
    int node = blockIdx.x * 4 + (threadIdx.x >> 6);
    if (node >= N) return;
    int lane = threadIdx.x & 63;
    int f2 = lane & 31;   // features 2*f2, 2*f2+1
    int ep = lane >> 5;   // edge parity
    int s = rowptr[node], e = rowptr[node + 1];
    float ax[8], ay[8];
#pragma unroll
    for (int k = 0; k < 8; ++k) { ax[k] = 0.f; ay[k] = 0.f; }
    int p = s;
    for (; p + 16 <= e; p += 16) {
#pragma unroll
        for (int k = 0; k < 8; ++k) {
            int j = col[p + 2 * k + ep];
            float2 f = __half22float2(*(const __half2*)(tp + (size_t)j * 64 + 2 * f2));
            ax[k] += f.x;
            ay[k] += f.y;
        }
    }
    for (int t = p + ep; t < e; t += 2) {
        int j = col[t];
        float2 f = __half22float2(*(const __half2*)(tp + (size_t)j * 64 + 2 * f2));
        ax[0] += f.x;
        ay[0] += f.y;
    }
    float sx = ((ax[0] + ax[1]) + (ax[2] + ax[3])) + ((ax[4] + ax[5]) + (ax[6] + ax[7]));
    float sy = ((ay[0] + ay[1]) + (ay[2] + ay[3])) + ((ay[4] + ay[5]) + (ay[6] + ay[7]));
    sx += __shfl_xor(sx, 32, 64);
    sy += __shfl_xor(sy, 32, 64);
    if (ep == 0) {
        float2 selfv = __half22float2(*(const __half2*)(tp + (size_t)node * 64 + 2 * f2));
        float di = dinv[node];
        float2 o;
        o.x = (sx + selfv.x) * di + bg[2 * f2];
        o.y = (sy + selfv.y) * di + bg[2 * f2 + 1];
        *(float2*)(out + (size_t)node * 64 + 2 * f2) = o;
    }
}

extern "C" void kernel_launch(void* const* d_in, const int* in_sizes, int n_in,
                              void* d_out, int out_size, void* d_ws, size_t ws_size,
                              hipStream_t stream) {
    const float* x = (const float*)d_in[0];
    const int* ei = (const int*)d_in[1];    // int32 per harness conversion
    const float* W1l = (const float*)d_in[2];
    const float* b1l = (const float*)d_in[3];
    const float* W1r = (const float*)d_in[4];
    const float* W2l = (const float*)d_in[5];
    const float* b2l = (const float*)d_in[6];
    const float* W2r = (const float*)d_in[7];
    const float* Wg  = (const float*)d_in[8];
    const float* bg  = (const float*)d_in[9];

    const int N = in_sizes[0] / 128;
    const int E = in_sizes[1] / 2;
    const int* srcp = ei;
    const int* dstp = ei + E;

    const int NB = (E + 8191) / 8192;
    const int BK = (N + 255) >> 8;
    const int len = BK * NB;

    // workspace layout
    float* ws = (float*)d_ws;
    float* dinv = ws;                            // N
    unsigned char* p8 = (unsigned char*)(dinv + N); // N*128 bytes (fp8 e4m3)
    __half* q16 = (__half*)(p8 + (size_t)N * 128);  // N*128 half
    __half* r16 = q16 + (size_t)N * 128;         // N*64 half
    __half* s16 = r16 + (size_t)N * 64;          // N*64 half
    __half* tp16 = s16 + (size_t)N * 64;         // N*64 half
    int* rowptr = (int*)(tp16 + (size_t)N * 64); // N+1
    int* off    = rowptr + (N + 1);              // len+2
    int* colbuf = off + len + 2;                 // E
    unsigned* ebuf = (unsigned*)(colbuf + E);    // E
    int* bsum   = (int*)(ebuf + E);              // 32
    uintptr_t up = (uintptr_t)(bsum + 32);
    up = (up + 15) & ~(uintptr_t)15;
    unsigned short* p1h = (unsigned short*)up;   // 32768 (128x256)
    unsigned short* p1l = p1h + 32768;
    unsigned short* p2h = p1l + 32768;           // 16384 (128x128)
    unsigned short* p2l = p2h + 16384;
    unsigned short* p3h = p2l + 16384;           // 4096 (64x64)
    unsigned short* p3l = p3h + 4096;

    float* out = (float*)d_out;

    // --- CSR build (radix by dst) ---
    count_kernel<<<NB, 256, 0, stream>>>(dstp, off, E, NB, BK);
    const int sn = len + 1;
    const int SBs = (sn + 2047) / 2048;
    scan_reduce_kernel<<<SBs, 256, 0, stream>>>(off, bsum, sn);
    scan_offsets_kernel<<<1, 64, 0, stream>>>(bsum, SBs);
    scan_final_kernel<<<SBs, 256, 0, stream>>>(off, bsum, sn);
    partition_kernel<<<NB, 256, 0, stream>>>(srcp, dstp, off, ebuf, E, NB, BK);
    finalize_kernel<<<BK, 256, 0, stream>>>(ebuf, off, colbuf, rowptr, dinv, N, NB, E);

    packw_kernel<<<dim3(64, 5), 256, 0, stream>>>(W1l, W1r, W2l, W2r, Wg,
                                                  p1h, p1l, p2h, p2l, p3h, p3l);

    const int gb  = (N + 63) / 64;   // gemm1: 64 nodes/block
    const int gbf = (N + 31) / 32;   // fused kernels: 32 nodes/block (pair-split)
    const int ab  = (N + 3) / 4;

    // gemm1: y=0 -> p8 (fp8), y=1 -> q16 (fp16)
    gemm1_kernel<<<dim3(gb, 2), 256, 0, stream>>>(x, p1h, p1l, p8, q16, N);

    // fused: h1 = relu(mean(p8)+q16+b1l); [r16|s16] = h1 @ [W2l|W2r]
    sage2_fused_kernel<<<gbf, 256, 0, stream>>>(p8, q16, rowptr, colbuf, b1l,
                                                p2h, p2l, r16, s16, N);

    // fused: h2 = softmax(mean(r16)+s16+b2l); tp16 = (h2 @ Wg) * dinv
    gcn_prep_fused_kernel<<<gbf, 256, 0, stream>>>(r16, s16, rowptr, colbuf, b2l,
                                                   p3h, p3l, dinv, tp16, N);

    gcn_agg_kernel<<<ab, 256, 0, stream>>>(tp16, rowptr, colbuf, dinv, bg, out, N);
}